// Round 1
// baseline (593.854 us; speedup 1.0000x reference)
//
#include <hip/hip_runtime.h>
#include <hip/hip_bf16.h>

typedef unsigned short u16;
typedef __attribute__((ext_vector_type(4))) float f32x4;
typedef __attribute__((ext_vector_type(8))) short bf16x8;
typedef __attribute__((ext_vector_type(8))) unsigned short u16x8;

#define B_    64
#define T_    2048
#define HID_  512
#define HCLS_ 1024
#define DOUT_ 10
#define M_    (B_ * T_)   // 131072 rows

// ---------- helpers ----------
__device__ __forceinline__ u16 f2bf(float x) {
  unsigned int u = __float_as_uint(x);
  u += 0x7FFFu + ((u >> 16) & 1u);        // round-to-nearest-even
  return (u16)(u >> 16);
}

__device__ __forceinline__ float fast_tanh(float x) {
  // tanh(x) = 1 - 2/(exp(2x)+1); exact at +-inf, ~1e-6 rel err via v_exp
  float e = __expf(2.0f * x);
  return 1.0f - __fdividef(2.0f, e + 1.0f);
}

// ---------- kernel 0: W [k,n] fp32 -> Wt [n,k] bf16 (n-major for B-frag reads) ----------
__global__ __launch_bounds__(256) void cvt_w_kernel(const float* __restrict__ W,
                                                    u16* __restrict__ Wt) {
  int o = blockIdx.x * 256 + threadIdx.x;   // 262144 total
  int n = o >> 9, k = o & 511;
  Wt[o] = f2bf(W[k * HID_ + n]);
}

// ---------- kernel 1: fused GEMM + tanh + dot(context) partial ----------
// C-tile 128x128, BK=32, 256 threads (4 waves, each 64x64 via 4x4 mfma_16x16x32_bf16).
// A (embedding, fp32) converted in-register -> LDS bf16. B staged via global_load_lds(16B).
// Epilogue: partial[m] = sum_n tanh(acc+bias[n])*cw[n] over this block's 128 cols -> atomicAdd.
__global__ __launch_bounds__(256) void gemm_score_kernel(
    const float* __restrict__ E, const u16* __restrict__ Wt,
    const float* __restrict__ bias, const float* __restrict__ cw,
    float* __restrict__ dots) {
  __shared__ u16 lA[128 * 32];   // [m][k]
  __shared__ u16 lB[128 * 32];   // [n][k]
  const int tid = threadIdx.x;
  const int n0 = blockIdx.x * 128;            // x fastest: 4 n-chunks share A tile (L3 reuse)
  const int m0 = blockIdx.y * 128;
  const int w = tid >> 6, l = tid & 63;
  const int wm = (w >> 1) * 64, wn = (w & 1) * 64;
  const int lm = l & 15, lg = l >> 4;

  f32x4 acc[4][4] = {};

  // A staging: thread covers 16 consecutive floats: row=tid/2, col=(tid&1)*16
  const int arow = tid >> 1;
  const int acol = (tid & 1) * 16;
  const float* aptr = E + (size_t)(m0 + arow) * HID_ + acol;
  u16* lA_w = lA + arow * 32 + acol;

  // B staging: two 16B global_load_lds issues per thread per K-step (lane-contiguous)
  const int bidx0 = tid * 8;
  const int bidx1 = 2048 + tid * 8;
  const u16* bptr0 = Wt + (size_t)(n0 + (bidx0 >> 5)) * HID_ + (bidx0 & 31);
  const u16* bptr1 = Wt + (size_t)(n0 + (bidx1 >> 5)) * HID_ + (bidx1 & 31);

  const u16* fa0 = lA + (wm + lm) * 32 + lg * 8;
  const u16* fb0 = lB + (wn + lm) * 32 + lg * 8;

  for (int k0 = 0; k0 < HID_; k0 += 32) {
    __builtin_amdgcn_global_load_lds(
        (const __attribute__((address_space(1))) unsigned int*)(bptr0 + k0),
        (__attribute__((address_space(3))) unsigned int*)(lB + bidx0), 16, 0, 0);
    __builtin_amdgcn_global_load_lds(
        (const __attribute__((address_space(1))) unsigned int*)(bptr1 + k0),
        (__attribute__((address_space(3))) unsigned int*)(lB + bidx1), 16, 0, 0);

    const float4* ap = (const float4*)(aptr + k0);
    float4 f0 = ap[0], f1 = ap[1], f2 = ap[2], f3 = ap[3];
    u16x8 v0, v1;
    v0[0] = f2bf(f0.x); v0[1] = f2bf(f0.y); v0[2] = f2bf(f0.z); v0[3] = f2bf(f0.w);
    v0[4] = f2bf(f1.x); v0[5] = f2bf(f1.y); v0[6] = f2bf(f1.z); v0[7] = f2bf(f1.w);
    v1[0] = f2bf(f2.x); v1[1] = f2bf(f2.y); v1[2] = f2bf(f2.z); v1[3] = f2bf(f2.w);
    v1[4] = f2bf(f3.x); v1[5] = f2bf(f3.y); v1[6] = f2bf(f3.z); v1[7] = f2bf(f3.w);
    *(u16x8*)(lA_w)     = v0;   // ds_write_b128
    *(u16x8*)(lA_w + 8) = v1;

    __syncthreads();   // drains vmcnt (load_lds) + lgkm (ds_write)

    bf16x8 af[4], bv[4];
#pragma unroll
    for (int i = 0; i < 4; ++i) af[i] = *(const bf16x8*)(fa0 + i * 16 * 32);
#pragma unroll
    for (int j = 0; j < 4; ++j) bv[j] = *(const bf16x8*)(fb0 + j * 16 * 32);
#pragma unroll
    for (int i = 0; i < 4; ++i)
#pragma unroll
      for (int j = 0; j < 4; ++j)
        acc[i][j] = __builtin_amdgcn_mfma_f32_16x16x32_bf16(af[i], bv[j], acc[i][j], 0, 0, 0);

    __syncthreads();   // tile consumed; safe to restage
  }

  // Epilogue. C/D layout (m89-verified): n = wn + j*16 + (l&15); m = wm + i*16 + (l>>4)*4 + r
  float bj[4], cj[4];
#pragma unroll
  for (int j = 0; j < 4; ++j) {
    int n = n0 + wn + j * 16 + lm;
    bj[j] = bias[n];
    cj[j] = cw[n];
  }
#pragma unroll
  for (int i = 0; i < 4; ++i) {
#pragma unroll
    for (int r = 0; r < 4; ++r) {
      float s = 0.f;
#pragma unroll
      for (int j = 0; j < 4; ++j) {
        float u = acc[i][j][r] + bj[j];
        s = fmaf(fast_tanh(u), cj[j], s);
      }
      // reduce over the 16 lanes holding this row's columns (xor within lane&15)
      s += __shfl_xor(s, 1, 64);
      s += __shfl_xor(s, 2, 64);
      s += __shfl_xor(s, 4, 64);
      s += __shfl_xor(s, 8, 64);
      if (lm == 0)
        atomicAdd(&dots[m0 + wm + i * 16 + lg * 4 + r], s);
    }
  }
}

// ---------- kernel 2: scores=tanh(dots); attn = softmax over T (tanh in (-1,1): no max needed) ----------
__global__ __launch_bounds__(256) void softmax_kernel(const float* __restrict__ dots,
                                                      float* __restrict__ attn) {
  int b = blockIdx.x, tid = threadIdx.x;
  float e[8];
  float sum = 0.f;
#pragma unroll
  for (int i = 0; i < 8; ++i) {
    float p = dots[b * T_ + i * 256 + tid];
    e[i] = __expf(fast_tanh(p));
    sum += e[i];
  }
#pragma unroll
  for (int m = 1; m < 64; m <<= 1) sum += __shfl_xor(sum, m, 64);
  __shared__ float ws4[4];
  if ((tid & 63) == 0) ws4[tid >> 6] = sum;
  __syncthreads();
  float inv = 1.f / (ws4[0] + ws4[1] + ws4[2] + ws4[3]);
#pragma unroll
  for (int i = 0; i < 8; ++i) attn[b * T_ + i * 256 + tid] = e[i] * inv;
}

// ---------- kernel 3: ctx[b,h] = sum_t attn[b,t]*E[b,t,h] (t-chunked, atomic accumulate) ----------
__global__ __launch_bounds__(256) void ctx_kernel(const float* __restrict__ E,
                                                  const float* __restrict__ attn,
                                                  float* __restrict__ ctxv) {
  int b = blockIdx.x;
  int col = blockIdx.y * 256 + threadIdx.x;
  int t0 = blockIdx.z * 256;
  const float* ep = E + ((size_t)b * T_ + t0) * HID_ + col;
  const float* ap = attn + b * T_ + t0;
  float acc = 0.f;
#pragma unroll 4
  for (int t = 0; t < 256; ++t) acc = fmaf(ap[t], ep[(size_t)t * HID_], acc);
  atomicAdd(&ctxv[b * HID_ + col], acc);
}

// ---------- kernel 4: classifier: relu(ctx@W1+b1)@W2+b2 -> softmax(10) ----------
__global__ __launch_bounds__(1024) void classifier_kernel(
    const float* __restrict__ ctxv, const float* __restrict__ W1,
    const float* __restrict__ b1, const float* __restrict__ W2,
    const float* __restrict__ b2, float* __restrict__ out) {
  __shared__ float sc[HID_];
  __shared__ float hbuf[HCLS_];
  __shared__ float lgs[DOUT_];
  int b = blockIdx.x, tid = threadIdx.x;
  if (tid < HID_) sc[tid] = ctxv[b * HID_ + tid];
  __syncthreads();
  float a = b1[tid];
#pragma unroll 8
  for (int k = 0; k < HID_; ++k) a = fmaf(sc[k], W1[k * HCLS_ + tid], a);
  hbuf[tid] = fmaxf(a, 0.f);
  __syncthreads();
  if (tid < 160) {   // 10 logits x 16 lanes each (groups 16-aligned within waves)
    int j = tid >> 4, p = tid & 15;
    float acc2 = 0.f;
    for (int k = p; k < HCLS_; k += 16) acc2 = fmaf(hbuf[k], W2[k * DOUT_ + j], acc2);
    acc2 += __shfl_xor(acc2, 1, 64);
    acc2 += __shfl_xor(acc2, 2, 64);
    acc2 += __shfl_xor(acc2, 4, 64);
    acc2 += __shfl_xor(acc2, 8, 64);
    if (p == 0) lgs[j] = acc2 + b2[j];
  }
  __syncthreads();
  if (tid == 0) {
    float mx = lgs[0];
#pragma unroll
    for (int j = 1; j < DOUT_; ++j) mx = fmaxf(mx, lgs[j]);
    float ex[DOUT_], s = 0.f;
#pragma unroll
    for (int j = 0; j < DOUT_; ++j) { ex[j] = __expf(lgs[j] - mx); s += ex[j]; }
    float inv = 1.f / s;
#pragma unroll
    for (int j = 0; j < DOUT_; ++j) out[b * DOUT_ + j] = ex[j] * inv;
  }
}

// ---------- launch ----------
extern "C" void kernel_launch(void* const* d_in, const int* in_sizes, int n_in,
                              void* d_out, int out_size, void* d_ws, size_t ws_size,
                              hipStream_t stream) {
  (void)in_sizes; (void)n_in; (void)out_size; (void)ws_size;
  // inputs: 0 numerical (unused by reference), 1 embedding, 2 weight, 3 bias,
  //         4 context_weight, 5 W1, 6 b1, 7 W2, 8 b2  (all fp32)
  const float* E    = (const float*)d_in[1];
  const float* W    = (const float*)d_in[2];
  const float* bias = (const float*)d_in[3];
  const float* cw   = (const float*)d_in[4];
  const float* W1   = (const float*)d_in[5];
  const float* b1   = (const float*)d_in[6];
  const float* W2   = (const float*)d_in[7];
  const float* b2   = (const float*)d_in[8];
  float* out = (float*)d_out;

  // ws layout (~1.7 MB): Wt16 | dots | attn | ctx
  u16*   Wt   = (u16*)d_ws;
  float* dots = (float*)((char*)d_ws + 524288);
  float* attn = (float*)((char*)d_ws + 1048576);
  float* ctxv = (float*)((char*)d_ws + 1572864);

  hipMemsetAsync(dots, 0, M_ * sizeof(float), stream);
  hipMemsetAsync(ctxv, 0, B_ * HID_ * sizeof(float), stream);

  cvt_w_kernel<<<(HID_ * HID_) / 256, 256, 0, stream>>>(W, Wt);
  gemm_score_kernel<<<dim3(4, M_ / 128), 256, 0, stream>>>(E, Wt, bias, cw, dots);
  softmax_kernel<<<B_, 256, 0, stream>>>(dots, attn);
  ctx_kernel<<<dim3(B_, 2, 8), 256, 0, stream>>>(E, attn, ctxv);
  classifier_kernel<<<B_, 1024, 0, stream>>>(ctxv, W1, b1, W2, b2, out);
}

// Round 2
// 578.180 us; speedup vs baseline: 1.0271x; 1.0271x over previous
//
#include <hip/hip_runtime.h>
#include <hip/hip_bf16.h>

typedef unsigned short u16;
typedef __attribute__((ext_vector_type(4))) float f32x4;
typedef __attribute__((ext_vector_type(8))) short bf16x8;
typedef __attribute__((ext_vector_type(8))) unsigned short u16x8;

#define B_    64
#define T_    2048
#define HID_  512
#define HCLS_ 1024
#define DOUT_ 10
#define M_    (B_ * T_)   // 131072 rows

// ---------- helpers ----------
// pack 2 floats -> 2 bf16 in one u32 (low u16 = a)
__device__ __forceinline__ unsigned f2bf2(float a, float b) {
#if __has_builtin(__builtin_amdgcn_cvt_pk_bf16_f32)
  auto r = __builtin_amdgcn_cvt_pk_bf16_f32(a, b);   // v_cvt_pk_bf16_f32 (RNE)
  unsigned u;
  __builtin_memcpy(&u, &r, 4);
  return u;
#else
  // round-half-up (max err 0.5 ulp, same as RNE) + v_perm pack: 3 VALU / 2 elems
  unsigned ua = __float_as_uint(a) + 0x8000u;
  unsigned ub = __float_as_uint(b) + 0x8000u;
  return __builtin_amdgcn_perm(ub, ua, 0x07060302);  // [ub.hi16 : ua.hi16]
#endif
}

__device__ __forceinline__ float fast_tanh(float x) {
  float e = __expf(2.0f * x);
  return 1.0f - __fdividef(2.0f, e + 1.0f);
}

// ---------- kernel 0: W [k,n] fp32 -> Wt [n,k] bf16, LDS-transposed (coalesced both sides) ----------
__global__ __launch_bounds__(256) void cvt_w_kernel(const float* __restrict__ W,
                                                    u16* __restrict__ Wt) {
  __shared__ float st[64][65];   // +1 pad: column reads conflict-free
  const int bk = blockIdx.x & 7, bn = blockIdx.x >> 3;   // 8x8 tiles of 64x64
  const int k0 = bk * 64, n0 = bn * 64;
  const int tid = threadIdx.x;
  const int kk = tid >> 4, nn = (tid & 15) * 4;
#pragma unroll
  for (int it = 0; it < 4; ++it) {
    float4 v = *(const float4*)(W + (size_t)(k0 + kk + it * 16) * HID_ + n0 + nn);
    st[kk + it * 16][nn + 0] = v.x;
    st[kk + it * 16][nn + 1] = v.y;
    st[kk + it * 16][nn + 2] = v.z;
    st[kk + it * 16][nn + 3] = v.w;
  }
  __syncthreads();
  const int nr = tid >> 3, kc = (tid & 7) * 8;
#pragma unroll
  for (int it = 0; it < 2; ++it) {
    int n = nr + it * 32;
    union { unsigned u[4]; u16x8 v; } r;
#pragma unroll
    for (int j = 0; j < 4; ++j)
      r.u[j] = f2bf2(st[kc + 2 * j][n], st[kc + 2 * j + 1][n]);
    *(u16x8*)(Wt + (size_t)(n0 + n) * HID_ + k0 + kc) = r.v;
  }
}

// ---------- kernel 1: fused GEMM + tanh + dot(context) partials ----------
// 128x128 tile, BK=32, 4 waves x (4x4) mfma_16x16x32_bf16.
// LDS layout XOR-swizzled: 16B chunk (row, c) stored at chunk index c ^ ((row>>1)&3)
// -> every 16-lane ds_read/ds_write phase is 2-way (free); global_load_lds stays
//    lane-contiguous on the LDS side (only the global source address is permuted).
__global__ __launch_bounds__(256) void gemm_score_kernel(
    const float* __restrict__ E, const u16* __restrict__ Wt,
    const float* __restrict__ bias, const float* __restrict__ cw,
    float* __restrict__ dots4) {
  __shared__ u16 lA[128 * 32];   // [m][k] swizzled
  __shared__ u16 lB[128 * 32];   // [n][k] swizzled
  const int tid = threadIdx.x;
  const int n0 = blockIdx.x * 128;   // x fastest: 4 n-chunks share A rows (L3 reuse)
  const int m0 = blockIdx.y * 128;
  const int w = tid >> 6, l = tid & 63;
  const int wm = (w >> 1) * 64, wn = (w & 1) * 64;
  const int lm = l & 15, lg = l >> 4;

  f32x4 acc[4][4] = {};

  // --- A staging: thread covers row=tid/2, 16 floats at col=(tid&1)*16 ---
  const int arow = tid >> 1;
  const int acol = (tid & 1) * 16;
  const float* aptr = E + (size_t)(m0 + arow) * HID_ + acol;
  const int ax = (arow >> 1) & 3;
  const int ac0 = 2 * (tid & 1);
  u16* aw0 = lA + arow * 32 + ((ac0 + 0) ^ ax) * 8;
  u16* aw1 = lA + arow * 32 + ((ac0 + 1) ^ ax) * 8;

  // --- B staging: 2 x global_load_lds(16B); physical slot p = instr*256 + tid ---
  const int p0 = tid, p1 = 256 + tid;
  const int br0 = p0 >> 2, bc0 = p0 & 3;
  const int br1 = p1 >> 2, bc1 = p1 & 3;
  const u16* bsrc0 = Wt + (size_t)(n0 + br0) * HID_ + (bc0 ^ ((br0 >> 1) & 3)) * 8;
  const u16* bsrc1 = Wt + (size_t)(n0 + br1) * HID_ + (bc1 ^ ((br1 >> 1) & 3)) * 8;
  u16* bdst0 = lB + p0 * 8;
  u16* bdst1 = lB + p1 * 8;

  // --- fragment read pointers (swizzle factor (lm>>1)&3 constant across j) ---
  const int fx = (lm >> 1) & 3;
  const u16* fa0 = lA + (wm + lm) * 32 + (lg ^ fx) * 8;
  const u16* fb0 = lB + (wn + lm) * 32 + (lg ^ fx) * 8;

  for (int k0 = 0; k0 < HID_; k0 += 32) {
    __builtin_amdgcn_global_load_lds(
        (const __attribute__((address_space(1))) unsigned int*)(bsrc0 + k0),
        (__attribute__((address_space(3))) unsigned int*)bdst0, 16, 0, 0);
    __builtin_amdgcn_global_load_lds(
        (const __attribute__((address_space(1))) unsigned int*)(bsrc1 + k0),
        (__attribute__((address_space(3))) unsigned int*)bdst1, 16, 0, 0);

    const float4* ap = (const float4*)(aptr + k0);
    float4 f0 = ap[0], f1 = ap[1], f2 = ap[2], f3 = ap[3];
    union { unsigned u[4]; u16x8 v; } r0, r1;
    r0.u[0] = f2bf2(f0.x, f0.y); r0.u[1] = f2bf2(f0.z, f0.w);
    r0.u[2] = f2bf2(f1.x, f1.y); r0.u[3] = f2bf2(f1.z, f1.w);
    r1.u[0] = f2bf2(f2.x, f2.y); r1.u[1] = f2bf2(f2.z, f2.w);
    r1.u[2] = f2bf2(f3.x, f3.y); r1.u[3] = f2bf2(f3.z, f3.w);
    *(u16x8*)aw0 = r0.v;   // ds_write_b128 (swizzled slots)
    *(u16x8*)aw1 = r1.v;

    __syncthreads();

    bf16x8 af[4], bv[4];
#pragma unroll
    for (int i = 0; i < 4; ++i) af[i] = *(const bf16x8*)(fa0 + i * 16 * 32);
#pragma unroll
    for (int j = 0; j < 4; ++j) bv[j] = *(const bf16x8*)(fb0 + j * 16 * 32);
#pragma unroll
    for (int i = 0; i < 4; ++i)
#pragma unroll
      for (int j = 0; j < 4; ++j)
        acc[i][j] = __builtin_amdgcn_mfma_f32_16x16x32_bf16(af[i], bv[j], acc[i][j], 0, 0, 0);

    __syncthreads();
  }

  // --- epilogue: rowsum over this block's 128 cols; cross-wave combine; plain store ---
  // C/D layout: n = wn + j*16 + lm ; m = wm + i*16 + lg*4 + r
  float bj[4], cj[4];
#pragma unroll
  for (int j = 0; j < 4; ++j) {
    int n = n0 + wn + j * 16 + lm;
    bj[j] = bias[n];
    cj[j] = cw[n];
  }
  float* sred = (float*)lA;   // reuse LDS (all reads drained by final barrier): [4][64]
#pragma unroll
  for (int i = 0; i < 4; ++i) {
#pragma unroll
    for (int r = 0; r < 4; ++r) {
      float s = 0.f;
#pragma unroll
      for (int j = 0; j < 4; ++j)
        s = fmaf(fast_tanh(acc[i][j][r] + bj[j]), cj[j], s);
      s += __shfl_xor(s, 1, 64);
      s += __shfl_xor(s, 2, 64);
      s += __shfl_xor(s, 4, 64);
      s += __shfl_xor(s, 8, 64);
      if (lm == 0) sred[w * 64 + i * 16 + lg * 4 + r] = s;
    }
  }
  __syncthreads();
  if (tid < 128) {
    float v = (tid < 64) ? sred[0 * 64 + tid] + sred[1 * 64 + tid]
                         : sred[2 * 64 + (tid - 64)] + sred[3 * 64 + (tid - 64)];
    dots4[(size_t)blockIdx.x * M_ + m0 + tid] = v;
  }
}

// ---------- kernel 2: scores=tanh(sum of 4 partials); softmax over T ----------
__global__ __launch_bounds__(256) void softmax_kernel(const float* __restrict__ dots4,
                                                      float* __restrict__ attn) {
  int b = blockIdx.x, tid = threadIdx.x;
  float e[8];
  float sum = 0.f;
#pragma unroll
  for (int i = 0; i < 8; ++i) {
    size_t idx = (size_t)b * T_ + i * 256 + tid;
    float p = dots4[idx] + dots4[M_ + idx] + dots4[2 * M_ + idx] + dots4[3 * M_ + idx];
    e[i] = __expf(fast_tanh(p));   // tanh in (-1,1): no max-subtract needed
    sum += e[i];
  }
#pragma unroll
  for (int m = 1; m < 64; m <<= 1) sum += __shfl_xor(sum, m, 64);
  __shared__ float ws4[4];
  if ((tid & 63) == 0) ws4[tid >> 6] = sum;
  __syncthreads();
  float inv = 1.f / (ws4[0] + ws4[1] + ws4[2] + ws4[3]);
#pragma unroll
  for (int i = 0; i < 8; ++i) attn[b * T_ + i * 256 + tid] = e[i] * inv;
}

// ---------- kernel 3: ctxp[tc][b][h] = sum over 256-t chunk of attn*E (atomic-free) ----------
__global__ __launch_bounds__(256) void ctx_kernel(const float* __restrict__ E,
                                                  const float* __restrict__ attn,
                                                  float* __restrict__ ctxp) {
  const int b = blockIdx.x, tc = blockIdx.y;   // 8 chunks x 256 t
  const int tid = threadIdx.x;
  __shared__ float sa[256];
  sa[tid] = attn[b * T_ + tc * 256 + tid];
  __syncthreads();
  const int rg = tid >> 7;              // row parity group
  const int col = (tid & 127) * 4;
  const float* ep = E + ((size_t)b * T_ + tc * 256 + rg) * HID_ + col;
  float4 acc = {0.f, 0.f, 0.f, 0.f};
#pragma unroll 8
  for (int i = 0; i < 128; ++i) {
    float a = sa[rg + 2 * i];
    float4 v = *(const float4*)(ep + (size_t)2 * i * HID_);
    acc.x = fmaf(a, v.x, acc.x);
    acc.y = fmaf(a, v.y, acc.y);
    acc.z = fmaf(a, v.z, acc.z);
    acc.w = fmaf(a, v.w, acc.w);
  }
  __shared__ float4 sacc[128];
  if (rg == 1) sacc[tid & 127] = acc;
  __syncthreads();
  if (rg == 0) {
    float4 o = sacc[tid];
    o.x += acc.x; o.y += acc.y; o.z += acc.z; o.w += acc.w;
    *(float4*)(ctxp + ((size_t)tc * B_ + b) * HID_ + col) = o;
  }
}

// ---------- kernel 4: classifier (sums the 8 ctx partials on load) ----------
__global__ __launch_bounds__(1024) void classifier_kernel(
    const float* __restrict__ ctxp, const float* __restrict__ W1,
    const float* __restrict__ b1, const float* __restrict__ W2,
    const float* __restrict__ b2, float* __restrict__ out) {
  __shared__ float sc[HID_];
  __shared__ float hbuf[HCLS_];
  __shared__ float lgs[DOUT_];
  int b = blockIdx.x, tid = threadIdx.x;
  if (tid < HID_) {
    float s = 0.f;
#pragma unroll
    for (int c = 0; c < 8; ++c) s += ctxp[((size_t)c * B_ + b) * HID_ + tid];
    sc[tid] = s;
  }
  __syncthreads();
  float a = b1[tid];
#pragma unroll 8
  for (int k = 0; k < HID_; ++k) a = fmaf(sc[k], W1[k * HCLS_ + tid], a);
  hbuf[tid] = fmaxf(a, 0.f);
  __syncthreads();
  if (tid < 160) {   // 10 logits x 16 lanes
    int j = tid >> 4, p = tid & 15;
    float acc2 = 0.f;
    for (int k = p; k < HCLS_; k += 16) acc2 = fmaf(hbuf[k], W2[k * DOUT_ + j], acc2);
    acc2 += __shfl_xor(acc2, 1, 64);
    acc2 += __shfl_xor(acc2, 2, 64);
    acc2 += __shfl_xor(acc2, 4, 64);
    acc2 += __shfl_xor(acc2, 8, 64);
    if (p == 0) lgs[j] = acc2 + b2[j];
  }
  __syncthreads();
  if (tid == 0) {
    float mx = lgs[0];
#pragma unroll
    for (int j = 1; j < DOUT_; ++j) mx = fmaxf(mx, lgs[j]);
    float ex[DOUT_], s = 0.f;
#pragma unroll
    for (int j = 0; j < DOUT_; ++j) { ex[j] = __expf(lgs[j] - mx); s += ex[j]; }
    float inv = 1.f / s;
#pragma unroll
    for (int j = 0; j < DOUT_; ++j) out[b * DOUT_ + j] = ex[j] * inv;
  }
}

// ---------- launch ----------
extern "C" void kernel_launch(void* const* d_in, const int* in_sizes, int n_in,
                              void* d_out, int out_size, void* d_ws, size_t ws_size,
                              hipStream_t stream) {
  (void)in_sizes; (void)n_in; (void)out_size; (void)ws_size;
  const float* E    = (const float*)d_in[1];
  const float* W    = (const float*)d_in[2];
  const float* bias = (const float*)d_in[3];
  const float* cw   = (const float*)d_in[4];
  const float* W1   = (const float*)d_in[5];
  const float* b1   = (const float*)d_in[6];
  const float* W2   = (const float*)d_in[7];
  const float* b2   = (const float*)d_in[8];
  float* out = (float*)d_out;

  // ws layout (4 MB): Wt 512K | dots4 2M | attn 512K | ctxp 1M  — all fully
  // rewritten every call (no dependence on poisoned contents, no memsets).
  u16*   Wt    = (u16*)d_ws;
  float* dots4 = (float*)((char*)d_ws + (512 << 10));
  float* attn  = (float*)((char*)d_ws + (2560 << 10));
  float* ctxp  = (float*)((char*)d_ws + (3072 << 10));

  cvt_w_kernel<<<64, 256, 0, stream>>>(W, Wt);
  gemm_score_kernel<<<dim3(4, M_ / 128), 256, 0, stream>>>(E, Wt, bias, cw, dots4);
  softmax_kernel<<<B_, 256, 0, stream>>>(dots4, attn);
  ctx_kernel<<<dim3(B_, 8), 256, 0, stream>>>(E, attn, ctxp);
  classifier_kernel<<<B_, 1024, 0, stream>>>(ctxp, W1, b1, W2, b2, out);
}

// Round 3
// 533.081 us; speedup vs baseline: 1.1140x; 1.0846x over previous
//
#include <hip/hip_runtime.h>
#include <hip/hip_bf16.h>

typedef unsigned short u16;
typedef __attribute__((ext_vector_type(4))) float f32x4;
typedef __attribute__((ext_vector_type(8))) short bf16x8;
typedef __attribute__((ext_vector_type(8))) unsigned short u16x8;
typedef __attribute__((ext_vector_type(4))) unsigned short u16x4;

#define B_    64
#define T_    2048
#define HID_  512
#define HCLS_ 1024
#define DOUT_ 10
#define M_    (B_ * T_)   // 131072 rows

// ---------- helpers ----------
__device__ __forceinline__ unsigned f2bf2(float a, float b) {
#if __has_builtin(__builtin_amdgcn_cvt_pk_bf16_f32)
  auto r = __builtin_amdgcn_cvt_pk_bf16_f32(a, b);
  unsigned u;
  __builtin_memcpy(&u, &r, 4);
  return u;
#else
  unsigned ua = __float_as_uint(a) + 0x8000u;
  unsigned ub = __float_as_uint(b) + 0x8000u;
  return __builtin_amdgcn_perm(ub, ua, 0x07060302);
#endif
}

__device__ __forceinline__ float fast_tanh(float x) {
  float e = __expf(2.0f * x);
  return 1.0f - __fdividef(2.0f, e + 1.0f);
}

// ---------- kernel 0: W [k,n] fp32 -> Wt2: MFMA-B-frag-contiguous bf16 ----------
// Wt2 unit = (jt, ks) pair: 64 lanes x 16 B; lane l holds B[k0+(l>>4)*8 .. +8][n=jt*16+(l&15)]
// offset = ((jt*16 + ks)*64 + l)*8 elems. A wave's frag load is then a perfectly
// coalesced global_load_dwordx4 at base + l*16.
__global__ __launch_bounds__(256) void cvt_w_kernel(const float* __restrict__ W,
                                                    u16* __restrict__ Wt2) {
  const int pair = blockIdx.x * 4 + (threadIdx.x >> 6);  // 0..511 = jt*16+ks
  const int l = threadIdx.x & 63;
  const int jt = pair >> 4, ks = pair & 15;
  const int n = jt * 16 + (l & 15);
  const int k0 = ks * 32 + (l >> 4) * 8;
  union { unsigned u[4]; u16x8 v; } r;
#pragma unroll
  for (int j = 0; j < 4; ++j)
    r.u[j] = f2bf2(W[(size_t)(k0 + 2 * j) * HID_ + n],
                   W[(size_t)(k0 + 2 * j + 1) * HID_ + n]);
  *(u16x8*)(Wt2 + (size_t)pair * 512 + l * 8) = r.v;
}

// ---------- kernel 1: fused GEMM + tanh + context-dot + exp + weighted-E partials ----------
// 2048 blocks x 512 threads (8 waves). M-tile 64, full N=512 (wave w owns cols w*64..+63),
// K-loop 16 steps of 32. A (fp32 E) staged progressively into 64 KB LDS (bf16, XOR-swizzled
// 16B chunks: phys = logical ^ (row&7)); loads carried 2 iters ahead in regs, ds_write 1 iter
// ahead. B frags register-double-buffered straight from L2-resident Wt2. Raw s_barrier with
// lgkmcnt(0) only -> global loads stay in flight across barriers (no vmcnt(0) drain).
// Epilogue: full dot per row -> e=exp(tanh(dot)) -> atomic num[b][:] += e*A_row, den[b] += e.
__global__ __launch_bounds__(512, 4) void gemm_fused_kernel(
    const float* __restrict__ E, const u16* __restrict__ Wt2,
    const float* __restrict__ bias, const float* __restrict__ cw,
    float* __restrict__ num, float* __restrict__ den) {
  __shared__ u16 lA[64 * 512];     // 64 KB
  __shared__ float red[8 * 64];
  __shared__ float earr[64];

  const int tid = threadIdx.x;
  const int m0 = blockIdx.x * 64;
  const int b = blockIdx.x >> 5;   // 32 blocks per batch element
  const int w = tid >> 6, l = tid & 63;
  const int lm = l & 15, lg = l >> 4;

  // A staging: thread covers row = tid>>3, 4 floats at (tid&7)*4 within each 32-k region
  const int arow = tid >> 3;
  const int akq = tid & 7;
  const float* aptr = E + (size_t)(m0 + arow) * HID_ + akq * 4;
  const int arx = arow & 7;
  u16* awbase = lA + arow * 512 + (akq & 1) * 4;

  // B frag base for this wave (jt = w*4 + j)
  const u16* bbase = Wt2 + (size_t)w * 32768 + (size_t)l * 8;

  f32x4 acc[4][4] = {};
  bf16x8 bvC[4], bvN[4];
  float4 aregO, aregN;

  // ---- preamble: stage region 0; load region 1 to regs; load B frags for ks=0 ----
  aregO = *(const float4*)(aptr);
  {
    union { unsigned u[2]; u16x4 v; } r;
    r.u[0] = f2bf2(aregO.x, aregO.y);
    r.u[1] = f2bf2(aregO.z, aregO.w);
    *(u16x4*)(awbase + (((akq >> 1)) ^ arx) * 8) = r.v;
  }
  aregO = *(const float4*)(aptr + 32);   // region 1
#pragma unroll
  for (int j = 0; j < 4; ++j)
    bvC[j] = *(const bf16x8*)(bbase + j * 8192);
  __asm__ __volatile__("s_waitcnt lgkmcnt(0)\n\ts_barrier" ::: "memory");

#pragma unroll
  for (int ks = 0; ks < 16; ++ks) {
    if (ks < 14) aregN = *(const float4*)(aptr + (ks + 2) * 32);
    if (ks < 15) {
#pragma unroll
      for (int j = 0; j < 4; ++j)
        bvN[j] = *(const bf16x8*)(bbase + j * 8192 + (ks + 1) * 512);
    }
    // A frags: row = i*16+lm, phys chunk = (ks*4+lg) ^ (lm&7) (row&7 == lm&7, i-invariant)
    const u16* abase = lA + lm * 512 + (((ks * 4 + lg) ^ (lm & 7)) * 8);
#pragma unroll
    for (int i = 0; i < 4; ++i) {
      bf16x8 af = *(const bf16x8*)(abase + i * 16 * 512);
#pragma unroll
      for (int j = 0; j < 4; ++j)
        acc[i][j] = __builtin_amdgcn_mfma_f32_16x16x32_bf16(af, bvC[j], acc[i][j], 0, 0, 0);
    }
    if (ks < 15) {   // write region ks+1 (loaded last iter); readers see it after barrier
      union { unsigned u[2]; u16x4 v; } r;
      r.u[0] = f2bf2(aregO.x, aregO.y);
      r.u[1] = f2bf2(aregO.z, aregO.w);
      *(u16x4*)(awbase + ((((ks + 1) * 4) + (akq >> 1)) ^ arx) * 8) = r.v;
    }
    aregO = aregN;
#pragma unroll
    for (int j = 0; j < 4; ++j) bvC[j] = bvN[j];
    __asm__ __volatile__("s_waitcnt lgkmcnt(0)\n\ts_barrier" ::: "memory");
  }

  // ---- epilogue ----
  __syncthreads();
  float bj[4], cj[4];
#pragma unroll
  for (int j = 0; j < 4; ++j) {
    int n = w * 64 + j * 16 + lm;
    bj[j] = bias[n];
    cj[j] = cw[n];
  }
  // per-wave 64-col partial of tanh-dot; C/D layout: col=lm, row = i*16 + lg*4 + r
#pragma unroll
  for (int i = 0; i < 4; ++i) {
#pragma unroll
    for (int r = 0; r < 4; ++r) {
      float s = 0.f;
#pragma unroll
      for (int j = 0; j < 4; ++j)
        s = fmaf(fast_tanh(acc[i][j][r] + bj[j]), cj[j], s);
      s += __shfl_xor(s, 1, 64);
      s += __shfl_xor(s, 2, 64);
      s += __shfl_xor(s, 4, 64);
      s += __shfl_xor(s, 8, 64);
      if (lm == 0) red[w * 64 + i * 16 + lg * 4 + r] = s;
    }
  }
  __syncthreads();
  if (tid < 64) {
    float d = 0.f;
#pragma unroll
    for (int ww = 0; ww < 8; ++ww) d += red[ww * 64 + tid];
    float e = __expf(fast_tanh(d));   // tanh in (-1,1): exp safe, no max-subtract
    earr[tid] = e;
    float se = e;
    se += __shfl_xor(se, 1, 64);
    se += __shfl_xor(se, 2, 64);
    se += __shfl_xor(se, 4, 64);
    se += __shfl_xor(se, 8, 64);
    se += __shfl_xor(se, 16, 64);
    se += __shfl_xor(se, 32, 64);
    if (tid == 0) atomicAdd(den + b, se);
  }
  __syncthreads();
  // num[b][col] += sum_rows e[r] * A[r][col]; thread: col-chunk c8=tid>>3 (8 cols), rows rb+8k
  {
    const int c8 = tid >> 3, rb = tid & 7;
    const u16* nbase = lA + rb * 512 + ((c8 ^ rb) * 8);   // phys chunk = c8 ^ (row&7), row&7==rb
    float a8[8] = {};
#pragma unroll
    for (int k = 0; k < 8; ++k) {
      int r = rb + 8 * k;
      float e = earr[r];
      u16x8 v = *(const u16x8*)(nbase + k * 8 * 512);
#pragma unroll
      for (int j = 0; j < 8; ++j)
        a8[j] = fmaf(e, __uint_as_float((unsigned)v[j] << 16), a8[j]);
    }
#pragma unroll
    for (int j = 0; j < 8; ++j) {
      a8[j] += __shfl_xor(a8[j], 1, 64);
      a8[j] += __shfl_xor(a8[j], 2, 64);
      a8[j] += __shfl_xor(a8[j], 4, 64);
    }
    if (rb == 0) {
#pragma unroll
      for (int j = 0; j < 8; ++j)
        atomicAdd(num + (size_t)b * HID_ + c8 * 8 + j, a8[j]);
    }
  }
}

// ---------- kernel 2: classifier: ctx=num/den -> relu(ctx@W1+b1)@W2+b2 -> softmax(10) ----------
__global__ __launch_bounds__(1024) void classifier_kernel(
    const float* __restrict__ num, const float* __restrict__ den,
    const float* __restrict__ W1, const float* __restrict__ b1,
    const float* __restrict__ W2, const float* __restrict__ b2,
    float* __restrict__ out) {
  __shared__ float sc[HID_];
  __shared__ float hbuf[HCLS_];
  __shared__ float lgs[DOUT_];
  int b = blockIdx.x, tid = threadIdx.x;
  if (tid < HID_) sc[tid] = num[(size_t)b * HID_ + tid] / den[b];
  __syncthreads();
  float a = b1[tid];
#pragma unroll 8
  for (int k = 0; k < HID_; ++k) a = fmaf(sc[k], W1[(size_t)k * HCLS_ + tid], a);
  hbuf[tid] = fmaxf(a, 0.f);
  __syncthreads();
  if (tid < 160) {   // 10 logits x 16 lanes
    int j = tid >> 4, p = tid & 15;
    float acc2 = 0.f;
    for (int k = p; k < HCLS_; k += 16) acc2 = fmaf(hbuf[k], W2[(size_t)k * DOUT_ + j], acc2);
    acc2 += __shfl_xor(acc2, 1, 64);
    acc2 += __shfl_xor(acc2, 2, 64);
    acc2 += __shfl_xor(acc2, 4, 64);
    acc2 += __shfl_xor(acc2, 8, 64);
    if (p == 0) lgs[j] = acc2 + b2[j];
  }
  __syncthreads();
  if (tid == 0) {
    float mx = lgs[0];
#pragma unroll
    for (int j = 1; j < DOUT_; ++j) mx = fmaxf(mx, lgs[j]);
    float ex[DOUT_], s = 0.f;
#pragma unroll
    for (int j = 0; j < DOUT_; ++j) { ex[j] = __expf(lgs[j] - mx); s += ex[j]; }
    float inv = 1.f / s;
#pragma unroll
    for (int j = 0; j < DOUT_; ++j) out[b * DOUT_ + j] = ex[j] * inv;
  }
}

// ---------- launch ----------
extern "C" void kernel_launch(void* const* d_in, const int* in_sizes, int n_in,
                              void* d_out, int out_size, void* d_ws, size_t ws_size,
                              hipStream_t stream) {
  (void)in_sizes; (void)n_in; (void)out_size; (void)ws_size;
  const float* E    = (const float*)d_in[1];
  const float* W    = (const float*)d_in[2];
  const float* bias = (const float*)d_in[3];
  const float* cw   = (const float*)d_in[4];
  const float* W1   = (const float*)d_in[5];
  const float* b1   = (const float*)d_in[6];
  const float* W2   = (const float*)d_in[7];
  const float* b2   = (const float*)d_in[8];
  float* out = (float*)d_out;

  // ws: Wt2 512K | num 128K | den 256B  (num+den zeroed each call)
  u16*   Wt2 = (u16*)d_ws;
  float* num = (float*)((char*)d_ws + (512 << 10));
  float* den = (float*)((char*)d_ws + (512 << 10) + B_ * HID_ * sizeof(float));

  hipMemsetAsync(num, 0, (B_ * HID_ + B_) * sizeof(float), stream);
  cvt_w_kernel<<<128, 256, 0, stream>>>(W, Wt2);
  gemm_fused_kernel<<<M_ / 64, 512, 0, stream>>>(E, Wt2, bias, cw, num, den);
  classifier_kernel<<<B_, 1024, 0, stream>>>(num, den, W1, b1, W2, b2, out);
}

// Round 4
// 511.943 us; speedup vs baseline: 1.1600x; 1.0413x over previous
//
#include <hip/hip_runtime.h>
#include <hip/hip_bf16.h>

typedef unsigned short u16;
typedef __attribute__((ext_vector_type(4))) float f32x4;
typedef __attribute__((ext_vector_type(8))) short bf16x8;
typedef __attribute__((ext_vector_type(8))) unsigned short u16x8;
typedef __attribute__((ext_vector_type(4))) unsigned short u16x4;

#define B_    64
#define T_    2048
#define HID_  512
#define HCLS_ 1024
#define DOUT_ 10
#define M_    (B_ * T_)   // 131072 rows

// ---------- helpers ----------
__device__ __forceinline__ unsigned f2bf2(float a, float b) {
#if __has_builtin(__builtin_amdgcn_cvt_pk_bf16_f32)
  auto r = __builtin_amdgcn_cvt_pk_bf16_f32(a, b);
  unsigned u;
  __builtin_memcpy(&u, &r, 4);
  return u;
#else
  unsigned ua = __float_as_uint(a) + 0x8000u;
  unsigned ub = __float_as_uint(b) + 0x8000u;
  return __builtin_amdgcn_perm(ub, ua, 0x07060302);
#endif
}

__device__ __forceinline__ float fast_tanh(float x) {
  float e = __expf(2.0f * x);
  return 1.0f - __fdividef(2.0f, e + 1.0f);
}

// ---------- kernel 0: W [k,n] fp32 -> Wt2: MFMA-B-frag-contiguous bf16 ----------
// Wt2 unit = (jt, ks): 64 lanes x 16 B; lane l holds B[k0 + (l>>4)*8 ..][n = jt*16 + (l&15)]
// offset = ((jt*16 + ks)*64 + l)*8 elems -> a wave's frag load is one coalesced dwordx4.
__global__ __launch_bounds__(256) void cvt_w_kernel(const float* __restrict__ W,
                                                    u16* __restrict__ Wt2) {
  const int pair = blockIdx.x * 4 + (threadIdx.x >> 6);  // 0..511 = jt*16+ks
  const int l = threadIdx.x & 63;
  const int jt = pair >> 4, ks = pair & 15;
  const int n = jt * 16 + (l & 15);
  const int k0 = ks * 32 + (l >> 4) * 8;
  union { unsigned u[4]; u16x8 v; } r;
#pragma unroll
  for (int j = 0; j < 4; ++j)
    r.u[j] = f2bf2(W[(size_t)(k0 + 2 * j) * HID_ + n],
                   W[(size_t)(k0 + 2 * j + 1) * HID_ + n]);
  *(u16x8*)(Wt2 + (size_t)pair * 512 + l * 8) = r.v;
}

// ---------- kernel 1: fused GEMM + tanh + context-dot + exp + weighted-E partials ----------
// 2048 blocks x 512 threads (8 waves). M-tile 64, full N=512 (wave w owns cols w*64..+63).
// Phase 1: stage ENTIRE 64x512 A tile fp32->bf16 into 64 KB LDS (XOR swizzle: 16B chunk c of
// row r at phys c^(r&7)), one __syncthreads. Phase 2: barrier-free K-loop — ds_read A frags +
// L2-hot B frags (1-iter register prefetch) + MFMA. No LDS writes, no E deps, no barriers.
// Live regs ~110 < 128 budget (launch_bounds 512,4) -> no scratch spills (R3's 72 KB/block).
__global__ __launch_bounds__(512, 4) void gemm_fused_kernel(
    const float* __restrict__ E, const u16* __restrict__ Wt2,
    const float* __restrict__ bias, const float* __restrict__ cw,
    float* __restrict__ num, float* __restrict__ den) {
  __shared__ u16 lA[64 * 512];     // 64 KB
  __shared__ float red[8 * 64];
  __shared__ float earr[64];

  const int tid = threadIdx.x;
  const int m0 = blockIdx.x * 64;
  const int b = blockIdx.x >> 5;   // 32 blocks per batch element
  const int w = tid >> 6, l = tid & 63;
  const int lm = l & 15, lg = l >> 4;

  // ---- phase 1: stage full A tile; two batches of 8 float4 (keeps live regs ~32+addr) ----
  const float* ag = E + (size_t)m0 * HID_ + tid * 4;
#pragma unroll
  for (int h = 0; h < 2; ++h) {
    float4 r[8];
#pragma unroll
    for (int s = 0; s < 8; ++s)
      r[s] = *(const float4*)(ag + (size_t)(h * 8 + s) * 2048);
#pragma unroll
    for (int s = 0; s < 8; ++s) {
      const int ss = h * 8 + s;
      const int row = ss * 4 + (tid >> 7);      // wave-uniform row per instruction
      const int c = (tid & 127) >> 1;           // logical 16B chunk
      const int phys = c ^ (row & 7);
      union { unsigned u[2]; u16x4 v; } t;
      t.u[0] = f2bf2(r[s].x, r[s].y);
      t.u[1] = f2bf2(r[s].z, r[s].w);
      *(u16x4*)(lA + row * 512 + phys * 8 + (tid & 1) * 4) = t.v;
    }
    __builtin_amdgcn_sched_barrier(0);   // keep the two batches from merging (reg pressure)
  }

  // B frag base for this wave (jt = w*4 + j); issue ks=0 frags before the barrier
  const u16* bbase = Wt2 + (size_t)w * 32768 + (size_t)l * 8;
  bf16x8 bvC[4], bvN[4];
#pragma unroll
  for (int j = 0; j < 4; ++j) bvC[j] = *(const bf16x8*)(bbase + j * 8192);

  __syncthreads();

  // ---- phase 2: barrier-free K-loop ----
  f32x4 acc[4][4] = {};
#pragma unroll
  for (int ks = 0; ks < 16; ++ks) {
    if (ks < 15) {
#pragma unroll
      for (int j = 0; j < 4; ++j)
        bvN[j] = *(const bf16x8*)(bbase + j * 8192 + (ks + 1) * 512);
    }
    // A frag row = i*16+lm, k-chunk = ks*4+lg, phys = chunk ^ (lm&7) (i-invariant)
    const u16* abase = lA + lm * 512 + (((ks * 4 + lg) ^ (lm & 7)) * 8);
#pragma unroll
    for (int i = 0; i < 4; ++i) {
      bf16x8 af = *(const bf16x8*)(abase + i * 16 * 512);
#pragma unroll
      for (int j = 0; j < 4; ++j)
        acc[i][j] = __builtin_amdgcn_mfma_f32_16x16x32_bf16(af, bvC[j], acc[i][j], 0, 0, 0);
    }
    if (ks < 15) {
#pragma unroll
      for (int j = 0; j < 4; ++j) bvC[j] = bvN[j];
    }
  }

  // ---- epilogue ----
  float bj[4], cj[4];
#pragma unroll
  for (int j = 0; j < 4; ++j) {
    int n = w * 64 + j * 16 + lm;
    bj[j] = bias[n];
    cj[j] = cw[n];
  }
  // per-wave 64-col partial of tanh-dot; C/D layout: col=lm, row = i*16 + lg*4 + r
#pragma unroll
  for (int i = 0; i < 4; ++i) {
#pragma unroll
    for (int r = 0; r < 4; ++r) {
      float s = 0.f;
#pragma unroll
      for (int j = 0; j < 4; ++j)
        s = fmaf(fast_tanh(acc[i][j][r] + bj[j]), cj[j], s);
      s += __shfl_xor(s, 1, 64);
      s += __shfl_xor(s, 2, 64);
      s += __shfl_xor(s, 4, 64);
      s += __shfl_xor(s, 8, 64);
      if (lm == 0) red[w * 64 + i * 16 + lg * 4 + r] = s;
    }
  }
  __syncthreads();
  if (tid < 64) {
    float d = 0.f;
#pragma unroll
    for (int ww = 0; ww < 8; ++ww) d += red[ww * 64 + tid];
    float e = __expf(fast_tanh(d));   // tanh in (-1,1): exp safe, no max-subtract
    earr[tid] = e;
    float se = e;
    se += __shfl_xor(se, 1, 64);
    se += __shfl_xor(se, 2, 64);
    se += __shfl_xor(se, 4, 64);
    se += __shfl_xor(se, 8, 64);
    se += __shfl_xor(se, 16, 64);
    se += __shfl_xor(se, 32, 64);
    if (tid == 0) atomicAdd(den + b, se);
  }
  __syncthreads();
  // num[b][col] += sum_rows e[r] * A[r][col]; lA unchanged since staging (no writes after)
  {
    const int c8 = tid >> 3, rb = tid & 7;
    const u16* nbase = lA + rb * 512 + ((c8 ^ rb) * 8);   // phys = c8 ^ (row&7), row&7 == rb
    float a8[8] = {};
#pragma unroll
    for (int k = 0; k < 8; ++k) {
      int r = rb + 8 * k;
      float e = earr[r];
      u16x8 v = *(const u16x8*)(nbase + k * 8 * 512);
#pragma unroll
      for (int j = 0; j < 8; ++j)
        a8[j] = fmaf(e, __uint_as_float((unsigned)v[j] << 16), a8[j]);
    }
#pragma unroll
    for (int j = 0; j < 8; ++j) {
      a8[j] += __shfl_xor(a8[j], 1, 64);
      a8[j] += __shfl_xor(a8[j], 2, 64);
      a8[j] += __shfl_xor(a8[j], 4, 64);
    }
    if (rb == 0) {
#pragma unroll
      for (int j = 0; j < 8; ++j)
        atomicAdd(num + (size_t)b * HID_ + c8 * 8 + j, a8[j]);
    }
  }
}

// ---------- kernel 2: classifier: ctx=num/den -> relu(ctx@W1+b1)@W2+b2 -> softmax(10) ----------
__global__ __launch_bounds__(1024) void classifier_kernel(
    const float* __restrict__ num, const float* __restrict__ den,
    const float* __restrict__ W1, const float* __restrict__ b1,
    const float* __restrict__ W2, const float* __restrict__ b2,
    float* __restrict__ out) {
  __shared__ float sc[HID_];
  __shared__ float hbuf[HCLS_];
  __shared__ float lgs[DOUT_];
  int b = blockIdx.x, tid = threadIdx.x;
  if (tid < HID_) sc[tid] = num[(size_t)b * HID_ + tid] / den[b];
  __syncthreads();
  float a = b1[tid];
#pragma unroll 8
  for (int k = 0; k < HID_; ++k) a = fmaf(sc[k], W1[(size_t)k * HCLS_ + tid], a);
  hbuf[tid] = fmaxf(a, 0.f);
  __syncthreads();
  if (tid < 160) {   // 10 logits x 16 lanes
    int j = tid >> 4, p = tid & 15;
    float acc2 = 0.f;
    for (int k = p; k < HCLS_; k += 16) acc2 = fmaf(hbuf[k], W2[(size_t)k * DOUT_ + j], acc2);
    acc2 += __shfl_xor(acc2, 1, 64);
    acc2 += __shfl_xor(acc2, 2, 64);
    acc2 += __shfl_xor(acc2, 4, 64);
    acc2 += __shfl_xor(acc2, 8, 64);
    if (p == 0) lgs[j] = acc2 + b2[j];
  }
  __syncthreads();
  if (tid == 0) {
    float mx = lgs[0];
#pragma unroll
    for (int j = 1; j < DOUT_; ++j) mx = fmaxf(mx, lgs[j]);
    float ex[DOUT_], s = 0.f;
#pragma unroll
    for (int j = 0; j < DOUT_; ++j) { ex[j] = __expf(lgs[j] - mx); s += ex[j]; }
    float inv = 1.f / s;
#pragma unroll
    for (int j = 0; j < DOUT_; ++j) out[b * DOUT_ + j] = ex[j] * inv;
  }
}

// ---------- launch ----------
extern "C" void kernel_launch(void* const* d_in, const int* in_sizes, int n_in,
                              void* d_out, int out_size, void* d_ws, size_t ws_size,
                              hipStream_t stream) {
  (void)in_sizes; (void)n_in; (void)out_size; (void)ws_size;
  const float* E    = (const float*)d_in[1];
  const float* W    = (const float*)d_in[2];
  const float* bias = (const float*)d_in[3];
  const float* cw   = (const float*)d_in[4];
  const float* W1   = (const float*)d_in[5];
  const float* b1   = (const float*)d_in[6];
  const float* W2   = (const float*)d_in[7];
  const float* b2   = (const float*)d_in[8];
  float* out = (float*)d_out;

  // ws: Wt2 512K | num 128K | den 256B  (num+den zeroed each call for the atomics)
  u16*   Wt2 = (u16*)d_ws;
  float* num = (float*)((char*)d_ws + (512 << 10));
  float* den = (float*)((char*)d_ws + (512 << 10) + B_ * HID_ * sizeof(float));

  hipMemsetAsync(num, 0, (B_ * HID_ + B_) * sizeof(float), stream);
  cvt_w_kernel<<<128, 256, 0, stream>>>(W, Wt2);
  gemm_fused_kernel<<<M_ / 64, 512, 0, stream>>>(E, Wt2, bias, cw, num, den);
  classifier_kernel<<<B_, 1024, 0, stream>>>(num, den, W1, b1, W2, b2, out);
}

// Round 5
// 503.374 us; speedup vs baseline: 1.1797x; 1.0170x over previous
//
#include <hip/hip_runtime.h>
#include <hip/hip_bf16.h>

typedef unsigned short u16;
typedef __attribute__((ext_vector_type(4))) float f32x4;
typedef __attribute__((ext_vector_type(8))) short bf16x8;
typedef __attribute__((ext_vector_type(8))) unsigned short u16x8;
typedef __attribute__((ext_vector_type(4))) unsigned short u16x4;

#define B_    64
#define T_    2048
#define HID_  512
#define HCLS_ 1024
#define DOUT_ 10
#define M_    (B_ * T_)   // 131072 rows

// ---------- helpers ----------
__device__ __forceinline__ unsigned f2bf2(float a, float b) {
#if __has_builtin(__builtin_amdgcn_cvt_pk_bf16_f32)
  auto r = __builtin_amdgcn_cvt_pk_bf16_f32(a, b);
  unsigned u;
  __builtin_memcpy(&u, &r, 4);
  return u;
#else
  unsigned ua = __float_as_uint(a) + 0x8000u;
  unsigned ub = __float_as_uint(b) + 0x8000u;
  return __builtin_amdgcn_perm(ub, ua, 0x07060302);
#endif
}

__device__ __forceinline__ float fast_tanh(float x) {
  float e = __expf(2.0f * x);
  return 1.0f - __fdividef(2.0f, e + 1.0f);
}

// ---------- kernel 0: W [k,n] fp32 -> Wt2: MFMA-B-frag-contiguous bf16 ----------
// Wt2 unit = (jt, ks): 64 lanes x 16 B; lane l holds B[k0 + (l>>4)*8 ..][n = jt*16 + (l&15)]
// offset = ((jt*16 + ks)*64 + l)*8 elems -> a wave's frag load is one coalesced dwordx4.
__global__ __launch_bounds__(256) void cvt_w_kernel(const float* __restrict__ W,
                                                    u16* __restrict__ Wt2) {
  const int pair = blockIdx.x * 4 + (threadIdx.x >> 6);  // 0..511 = jt*16+ks
  const int l = threadIdx.x & 63;
  const int jt = pair >> 4, ks = pair & 15;
  const int n = jt * 16 + (l & 15);
  const int k0 = ks * 32 + (l >> 4) * 8;
  union { unsigned u[4]; u16x8 v; } r;
#pragma unroll
  for (int j = 0; j < 4; ++j)
    r.u[j] = f2bf2(W[(size_t)(k0 + 2 * j) * HID_ + n],
                   W[(size_t)(k0 + 2 * j + 1) * HID_ + n]);
  *(u16x8*)(Wt2 + (size_t)pair * 512 + l * 8) = r.v;
}

// ---------- kernel 1: fused GEMM + tanh + context-dot + exp + weighted-E partials ----------
// 2048 blocks x 512 threads (8 waves). M-tile 64, full N=512 (wave w owns cols w*64..+63).
// Phase 1: ALL 16 float4 E-loads issued at once (64 regs live; acc not yet allocated), then
// cvt+swizzled ds_write as they land; one __syncthreads. Phase 2: K-loop kept as a real loop
// (#pragma unroll 1 -> no cross-iter hoisting -> live set ~112 < 128, no scratch spill, unlike
// R4's 20 KB/block). B frags from L2-resident Wt2 via two rotating buffers, refill distance
// ~1 full iter (~2x L2 latency cover), zero register copies. No barriers, no LDS writes.
__global__ __launch_bounds__(512, 4) void gemm_fused_kernel(
    const float* __restrict__ E, const u16* __restrict__ Wt2,
    const float* __restrict__ bias, const float* __restrict__ cw,
    float* __restrict__ num, float* __restrict__ den) {
  __shared__ u16 lA[64 * 512];     // 64 KB
  __shared__ float red[8 * 64];
  __shared__ float earr[64];

  const int tid = threadIdx.x;
  const int m0 = blockIdx.x * 64;
  const int b = blockIdx.x >> 5;   // 32 blocks per batch element
  const int w = tid >> 6, l = tid & 63;
  const int lm = l & 15, lg = l >> 4;

  // ---- phase 1: stage full 64x512 A tile (fp32 -> bf16, XOR swizzle c^(row&7)) ----
  {
    const float* ag = E + (size_t)m0 * HID_ + tid * 4;
    float4 r[16];
#pragma unroll
    for (int s = 0; s < 16; ++s)
      r[s] = *(const float4*)(ag + (size_t)s * 2048);   // all 16 in flight
#pragma unroll
    for (int s = 0; s < 16; ++s) {
      const int row = s * 4 + (tid >> 7);
      const int c = (tid & 127) >> 1;
      const int phys = c ^ (row & 7);
      union { unsigned u[2]; u16x4 v; } t;
      t.u[0] = f2bf2(r[s].x, r[s].y);
      t.u[1] = f2bf2(r[s].z, r[s].w);
      *(u16x4*)(lA + row * 512 + phys * 8 + (tid & 1) * 4) = t.v;
    }
  }

  // B frag base (jt = w*4 + j); prologue: ks=0 -> bv0, ks=1 -> bv1 (global: pre-barrier ok)
  const u16* bbase = Wt2 + (size_t)w * 32768 + (size_t)l * 8;
  bf16x8 bv0[4], bv1[4];
#pragma unroll
  for (int j = 0; j < 4; ++j) bv0[j] = *(const bf16x8*)(bbase + j * 8192);
#pragma unroll
  for (int j = 0; j < 4; ++j) bv1[j] = *(const bf16x8*)(bbase + j * 8192 + 512);

  __syncthreads();

  // ---- phase 2: K-loop, 8 iterations of 2 K-steps ----
  f32x4 acc[4][4] = {};
#pragma unroll 1
  for (int ks = 0; ks < 16; ks += 2) {
    {   // step ks: consume bv0, refill bv0 with ks+2
      const u16* abase = lA + lm * 512 + (((ks * 4 + lg) ^ (lm & 7)) * 8);
#pragma unroll
      for (int i = 0; i < 4; ++i) {
        bf16x8 af = *(const bf16x8*)(abase + i * 16 * 512);
#pragma unroll
        for (int j = 0; j < 4; ++j)
          acc[i][j] = __builtin_amdgcn_mfma_f32_16x16x32_bf16(af, bv0[j], acc[i][j], 0, 0, 0);
      }
      if (ks + 2 < 16) {
#pragma unroll
        for (int j = 0; j < 4; ++j)
          bv0[j] = *(const bf16x8*)(bbase + j * 8192 + (size_t)(ks + 2) * 512);
      }
    }
    {   // step ks+1: consume bv1, refill bv1 with ks+3
      const u16* abase = lA + lm * 512 + ((((ks + 1) * 4 + lg) ^ (lm & 7)) * 8);
#pragma unroll
      for (int i = 0; i < 4; ++i) {
        bf16x8 af = *(const bf16x8*)(abase + i * 16 * 512);
#pragma unroll
        for (int j = 0; j < 4; ++j)
          acc[i][j] = __builtin_amdgcn_mfma_f32_16x16x32_bf16(af, bv1[j], acc[i][j], 0, 0, 0);
      }
      if (ks + 3 < 16) {
#pragma unroll
        for (int j = 0; j < 4; ++j)
          bv1[j] = *(const bf16x8*)(bbase + j * 8192 + (size_t)(ks + 3) * 512);
      }
    }
  }

  // ---- epilogue ----
  float bj[4], cj[4];
#pragma unroll
  for (int j = 0; j < 4; ++j) {
    int n = w * 64 + j * 16 + lm;
    bj[j] = bias[n];
    cj[j] = cw[n];
  }
  // per-wave 64-col partial of tanh-dot; C/D layout: col=lm, row = i*16 + lg*4 + r
#pragma unroll
  for (int i = 0; i < 4; ++i) {
#pragma unroll
    for (int r = 0; r < 4; ++r) {
      float s = 0.f;
#pragma unroll
      for (int j = 0; j < 4; ++j)
        s = fmaf(fast_tanh(acc[i][j][r] + bj[j]), cj[j], s);
      s += __shfl_xor(s, 1, 64);
      s += __shfl_xor(s, 2, 64);
      s += __shfl_xor(s, 4, 64);
      s += __shfl_xor(s, 8, 64);
      if (lm == 0) red[w * 64 + i * 16 + lg * 4 + r] = s;
    }
  }
  __syncthreads();
  if (tid < 64) {
    float d = 0.f;
#pragma unroll
    for (int ww = 0; ww < 8; ++ww) d += red[ww * 64 + tid];
    float e = __expf(fast_tanh(d));   // tanh in (-1,1): exp safe, no max-subtract
    earr[tid] = e;
    float se = e;
    se += __shfl_xor(se, 1, 64);
    se += __shfl_xor(se, 2, 64);
    se += __shfl_xor(se, 4, 64);
    se += __shfl_xor(se, 8, 64);
    se += __shfl_xor(se, 16, 64);
    se += __shfl_xor(se, 32, 64);
    if (tid == 0) atomicAdd(den + b, se);
  }
  __syncthreads();
  // num[b][col] += sum_rows e[r] * A[r][col]; lA unchanged since staging (no writes after)
  {
    const int c8 = tid >> 3, rb = tid & 7;
    const u16* nbase = lA + rb * 512 + ((c8 ^ rb) * 8);   // phys = c8 ^ (row&7), row&7 == rb
    float a8[8] = {};
#pragma unroll
    for (int k = 0; k < 8; ++k) {
      int r = rb + 8 * k;
      float e = earr[r];
      u16x8 v = *(const u16x8*)(nbase + k * 8 * 512);
#pragma unroll
      for (int j = 0; j < 8; ++j)
        a8[j] = fmaf(e, __uint_as_float((unsigned)v[j] << 16), a8[j]);
    }
#pragma unroll
    for (int j = 0; j < 8; ++j) {
      a8[j] += __shfl_xor(a8[j], 1, 64);
      a8[j] += __shfl_xor(a8[j], 2, 64);
      a8[j] += __shfl_xor(a8[j], 4, 64);
    }
    if (rb == 0) {
#pragma unroll
      for (int j = 0; j < 8; ++j)
        atomicAdd(num + (size_t)b * HID_ + c8 * 8 + j, a8[j]);
    }
  }
}

// ---------- kernel 2: classifier: ctx=num/den -> relu(ctx@W1+b1)@W2+b2 -> softmax(10) ----------
__global__ __launch_bounds__(1024) void classifier_kernel(
    const float* __restrict__ num, const float* __restrict__ den,
    const float* __restrict__ W1, const float* __restrict__ b1,
    const float* __restrict__ W2, const float* __restrict__ b2,
    float* __restrict__ out) {
  __shared__ float sc[HID_];
  __shared__ float hbuf[HCLS_];
  __shared__ float lgs[DOUT_];
  int b = blockIdx.x, tid = threadIdx.x;
  if (tid < HID_) sc[tid] = num[(size_t)b * HID_ + tid] / den[b];
  __syncthreads();
  float a = b1[tid];
#pragma unroll 8
  for (int k = 0; k < HID_; ++k) a = fmaf(sc[k], W1[(size_t)k * HCLS_ + tid], a);
  hbuf[tid] = fmaxf(a, 0.f);
  __syncthreads();
  if (tid < 160) {   // 10 logits x 16 lanes
    int j = tid >> 4, p = tid & 15;
    float acc2 = 0.f;
    for (int k = p; k < HCLS_; k += 16) acc2 = fmaf(hbuf[k], W2[(size_t)k * DOUT_ + j], acc2);
    acc2 += __shfl_xor(acc2, 1, 64);
    acc2 += __shfl_xor(acc2, 2, 64);
    acc2 += __shfl_xor(acc2, 4, 64);
    acc2 += __shfl_xor(acc2, 8, 64);
    if (p == 0) lgs[j] = acc2 + b2[j];
  }
  __syncthreads();
  if (tid == 0) {
    float mx = lgs[0];
#pragma unroll
    for (int j = 1; j < DOUT_; ++j) mx = fmaxf(mx, lgs[j]);
    float ex[DOUT_], s = 0.f;
#pragma unroll
    for (int j = 0; j < DOUT_; ++j) { ex[j] = __expf(lgs[j] - mx); s += ex[j]; }
    float inv = 1.f / s;
#pragma unroll
    for (int j = 0; j < DOUT_; ++j) out[b * DOUT_ + j] = ex[j] * inv;
  }
}

// ---------- launch ----------
extern "C" void kernel_launch(void* const* d_in, const int* in_sizes, int n_in,
                              void* d_out, int out_size, void* d_ws, size_t ws_size,
                              hipStream_t stream) {
  (void)in_sizes; (void)n_in; (void)out_size; (void)ws_size;
  const float* E    = (const float*)d_in[1];
  const float* W    = (const float*)d_in[2];
  const float* bias = (const float*)d_in[3];
  const float* cw   = (const float*)d_in[4];
  const float* W1   = (const float*)d_in[5];
  const float* b1   = (const float*)d_in[6];
  const float* W2   = (const float*)d_in[7];
  const float* b2   = (const float*)d_in[8];
  float* out = (float*)d_out;

  // ws: Wt2 512K | num 128K | den 256B  (num+den zeroed each call for the atomics)
  u16*   Wt2 = (u16*)d_ws;
  float* num = (float*)((char*)d_ws + (512 << 10));
  float* den = (float*)((char*)d_ws + (512 << 10) + B_ * HID_ * sizeof(float));

  hipMemsetAsync(num, 0, (B_ * HID_ + B_) * sizeof(float), stream);
  cvt_w_kernel<<<128, 256, 0, stream>>>(W, Wt2);
  gemm_fused_kernel<<<M_ / 64, 512, 0, stream>>>(E, Wt2, bias, cw, num, den);
  classifier_kernel<<<B_, 1024, 0, stream>>>(num, den, W1, b1, W2, b2, out);
}